// Round 15
// baseline (122.407 us; speedup 1.0000x reference)
//
#include <hip/hip_runtime.h>

#define DIN 256
#define DHID 256
#define DEDGE 64
#define BS 136      // bf16 LDS tile row stride (shorts), 128-col tiles: 272 B
#define BS2 72      // bf16 LDS tile row stride (shorts), 64-col tiles: 144 B

typedef float f32x4 __attribute__((ext_vector_type(4)));
typedef short s16x8 __attribute__((ext_vector_type(8)));
typedef unsigned int u32x2 __attribute__((ext_vector_type(2)));
typedef unsigned int u32x4 __attribute__((ext_vector_type(4)));

// HW RNE pack: dst = {bf16(lo), bf16(hi)}
__device__ __forceinline__ unsigned int cvtpk(float lo, float hi) {
    unsigned int r;
    asm("v_cvt_pk_bf16_f32 %0, %1, %2" : "=v"(r) : "v"(lo), "v"(hi));
    return r;
}

// split fp32x4 -> hi bf16 pair + lo bf16 pair (bf16x3 decomposition)
__device__ __forceinline__ void split4(const f32x4 v, u32x2& hi, u32x2& lo) {
    const unsigned int h0 = cvtpk(v[0], v[1]), h1 = cvtpk(v[2], v[3]);
    f32x4 hf;
    hf[0] = __builtin_bit_cast(float, h0 << 16);
    hf[1] = __builtin_bit_cast(float, h0 & 0xffff0000u);
    hf[2] = __builtin_bit_cast(float, h1 << 16);
    hf[3] = __builtin_bit_cast(float, h1 & 0xffff0000u);
    const f32x4 l = v - hf;
    hi = (u32x2){h0, h1};
    lo = (u32x2){cvtpk(l[0], l[1]), cvtpk(l[2], l[3])};
}

// -------- Kernel 1 (MFMA bf16x3): hp[kc][m][n] = sum_{k in 64-chunk kc} x[m][k]*Win[n][k]
// EXACT R6 version: grid (16 mt, 4 nt, 5): z<4 = GEMM K-chunks (256 blocks);
// z==4 = W2->fragment-order precompute spread over the 64 (x,y) blocks.
__global__ __launch_bounds__(256) void k_xh(
    const float* __restrict__ x, const float* __restrict__ Win,
    float* __restrict__ hp, const float* __restrict__ W2, s16x8* __restrict__ W2f)
{
    const int tid = threadIdx.x;
    if (blockIdx.z == 4) {
        if (tid < 32) {
            const int f = (((blockIdx.x << 2) + blockIdx.y) << 5) + tid;
            const int l15f = f & 15, qf = (f >> 4) & 3, ebf = (f >> 6) & 3, k0f = f >> 8;
            const int row = (ebf << 4) + l15f;
            const int col = (k0f << 5) + (qf << 3);
            const f32x4 w0 = *reinterpret_cast<const f32x4*>(&W2[row * DHID + col]);
            const f32x4 w1 = *reinterpret_cast<const f32x4*>(&W2[row * DHID + col + 4]);
            u32x4 wp;
            wp[0] = cvtpk(w0[0], w0[1]); wp[1] = cvtpk(w0[2], w0[3]);
            wp[2] = cvtpk(w1[0], w1[1]); wp[3] = cvtpk(w1[2], w1[3]);
            W2f[f] = __builtin_bit_cast(s16x8, wp);
        }
        return;
    }

    __shared__ unsigned short Ahi[64 * BS2], Alo[64 * BS2];
    __shared__ unsigned short Bhi[64 * BS2], Blo[64 * BS2];   // 4 x 9.2 KB = 36.9 KB
    const int m0 = blockIdx.x << 6, n0 = blockIdx.y << 6, k0 = blockIdx.z << 6;

    const int srow = tid >> 2, sc0 = (tid & 3) << 2;
    {
        const float* xA = x + (m0 + srow) * DIN + k0 + sc0;
        const float* wB = Win + (n0 + srow) * DIN + k0 + sc0;
#pragma unroll
        for (int g2 = 0; g2 < 4; ++g2) {
            const int c = g2 << 4;
            const int la = srow * BS2 + sc0 + c;
            u32x2 hi, lo;
            split4(*reinterpret_cast<const f32x4*>(xA + c), hi, lo);
            *reinterpret_cast<u32x2*>(&Ahi[la]) = hi;
            *reinterpret_cast<u32x2*>(&Alo[la]) = lo;
            split4(*reinterpret_cast<const f32x4*>(wB + c), hi, lo);
            *reinterpret_cast<u32x2*>(&Bhi[la]) = hi;
            *reinterpret_cast<u32x2*>(&Blo[la]) = lo;
        }
    }
    __syncthreads();

    const int lane = tid & 63, wave = tid >> 6, quad = lane >> 4, l15 = lane & 15;
    const int arow = (wave << 4) + l15;

    f32x4 acc[4];
#pragma unroll
    for (int nb = 0; nb < 4; ++nb) acc[nb] = (f32x4){0.f, 0.f, 0.f, 0.f};

#pragma unroll
    for (int ks = 0; ks < 2; ++ks) {
        const int kcol = (ks << 5) + (quad << 3);
        const s16x8 ahi = *reinterpret_cast<const s16x8*>(&Ahi[arow * BS2 + kcol]);
        const s16x8 alo = *reinterpret_cast<const s16x8*>(&Alo[arow * BS2 + kcol]);
#pragma unroll
        for (int nb = 0; nb < 4; ++nb) {
            const int brow = (nb << 4) + l15;
            const s16x8 bhi = *reinterpret_cast<const s16x8*>(&Bhi[brow * BS2 + kcol]);
            const s16x8 blo = *reinterpret_cast<const s16x8*>(&Blo[brow * BS2 + kcol]);
            acc[nb] = __builtin_amdgcn_mfma_f32_16x16x32_bf16(ahi, bhi, acc[nb], 0, 0, 0);
            acc[nb] = __builtin_amdgcn_mfma_f32_16x16x32_bf16(ahi, blo, acc[nb], 0, 0, 0);
            acc[nb] = __builtin_amdgcn_mfma_f32_16x16x32_bf16(alo, bhi, acc[nb], 0, 0, 0);
        }
    }

    float* dst = hp + ((size_t)blockIdx.z << 18);
    const int mrow = m0 + (wave << 4) + (quad << 2);
#pragma unroll
    for (int nb = 0; nb < 4; ++nb)
#pragma unroll
        for (int r = 0; r < 4; ++r)
            dst[(mrow + r) * DHID + n0 + (nb << 4) + l15] = acc[nb][r];
}

// -------- Kernel 2 (MFMA bf16x3): pap/pbp[kc][m][g], EXACT R6/R12 version.
__global__ __launch_bounds__(256) void k_pab(
    const float* __restrict__ hp, const float* __restrict__ W1,
    const float* __restrict__ bin, float* __restrict__ pap, float* __restrict__ pbp)
{
    __shared__ unsigned short Ahi[64 * BS], Alo[64 * BS];
    __shared__ unsigned short Bhi[64 * BS], Blo[64 * BS];   // 4 x 17.4 KB = 69.6 KB
    const int m0 = blockIdx.x << 6;
    const int half = blockIdx.y >> 2;
    const int n0 = (blockIdx.y & 3) << 6;
    const int kc = blockIdx.z;
    const int tid = threadIdx.x;
    const int k0 = kc << 7;

    const int srow = tid >> 2, sc0 = (tid & 3) << 2;
    {
        const float* hpA = hp + (m0 + srow) * DHID + k0 + sc0;
        const float* w1B = W1 + (n0 + srow) * 512 + (half << 8) + k0 + sc0;
        const float* binp = bin + k0 + sc0;
#pragma unroll
        for (int g2 = 0; g2 < 8; ++g2) {
            const int c = g2 << 4;
            f32x4 av = *reinterpret_cast<const f32x4*>(hpA + c);
            av += *reinterpret_cast<const f32x4*>(hpA + c + (1 << 18));
            av += *reinterpret_cast<const f32x4*>(hpA + c + (2 << 18));
            av += *reinterpret_cast<const f32x4*>(hpA + c + (3 << 18));
            av += *reinterpret_cast<const f32x4*>(binp + c);
            const int la = srow * BS + sc0 + c;
            u32x2 hi, lo;
            split4(av, hi, lo);
            *reinterpret_cast<u32x2*>(&Ahi[la]) = hi;
            *reinterpret_cast<u32x2*>(&Alo[la]) = lo;
            split4(*reinterpret_cast<const f32x4*>(w1B + c), hi, lo);
            *reinterpret_cast<u32x2*>(&Bhi[la]) = hi;
            *reinterpret_cast<u32x2*>(&Blo[la]) = lo;
        }
    }
    __syncthreads();

    const int lane = tid & 63, wave = tid >> 6, quad = lane >> 4, l15 = lane & 15;
    const int arow = (wave << 4) + l15;

    f32x4 acc[4];
#pragma unroll
    for (int nb = 0; nb < 4; ++nb) acc[nb] = (f32x4){0.f, 0.f, 0.f, 0.f};

#pragma unroll
    for (int ks = 0; ks < 4; ++ks) {
        const int kcol = (ks << 5) + (quad << 3);
        const s16x8 ahi = *reinterpret_cast<const s16x8*>(&Ahi[arow * BS + kcol]);
        const s16x8 alo = *reinterpret_cast<const s16x8*>(&Alo[arow * BS + kcol]);
#pragma unroll
        for (int nb = 0; nb < 4; ++nb) {
            const int brow = (nb << 4) + l15;
            const s16x8 bhi = *reinterpret_cast<const s16x8*>(&Bhi[brow * BS + kcol]);
            const s16x8 blo = *reinterpret_cast<const s16x8*>(&Blo[brow * BS + kcol]);
            acc[nb] = __builtin_amdgcn_mfma_f32_16x16x32_bf16(ahi, bhi, acc[nb], 0, 0, 0);
            acc[nb] = __builtin_amdgcn_mfma_f32_16x16x32_bf16(ahi, blo, acc[nb], 0, 0, 0);
            acc[nb] = __builtin_amdgcn_mfma_f32_16x16x32_bf16(alo, bhi, acc[nb], 0, 0, 0);
        }
    }

    float* dst = (half ? pbp : pap) + ((size_t)kc << 18);
    const int mrow = m0 + (wave << 4) + (quad << 2);
#pragma unroll
    for (int nb = 0; nb < 4; ++nb)
#pragma unroll
        for (int r = 0; r < 4; ++r)
            dst[(mrow + r) * DHID + n0 + (nb << 4) + l15] = acc[nb][r];
}

// -------- Kernel 3: fused z=silu(pa_i+pb_j+b1); out = z@W2^T + b2 (MFMA) ----
// EXACT R12 structure (runtime k0 loop, 1-deep pb pipeline, grid (4,64,4),
// plain stores). NEW: batched reciprocal — 1 v_rcp per 8 sigmoids via exact
// product-tree algebra (1/d_i = rcp(Πd) · Π_{j≠i}d_j). Trans ops per
// 8-elem group: 16 -> 9. fmaxf(z,-18) clamp guards product overflow
// (only affects z<-18 where silu < 3e-7).
__global__ __launch_bounds__(256) void k_out(
    const float* __restrict__ pap, const float* __restrict__ pbp,
    const float* __restrict__ b1, const s16x8* __restrict__ W2f,
    const float* __restrict__ b2, float* __restrict__ out)
{
    __shared__ s16x8 w2s[2048];      // 32 KB, fragment layout
    __shared__ float pab1[4][DHID];  // 4 KB

    const int jb = blockIdx.x, i0 = blockIdx.y << 2, b = blockIdx.z;
    const int tid = threadIdx.x;

    {
        const float b1v = b1[tid];
#pragma unroll
        for (int ii = 0; ii < 4; ++ii) {
            const int off = (((b << 8) + i0 + ii) << 8) + tid;
            pab1[ii][tid] = pap[off] + pap[off + (1 << 18)] + b1v;
        }
    }
#pragma unroll
    for (int it = 0; it < 8; ++it)
        w2s[tid + (it << 8)] = W2f[tid + (it << 8)];
    __syncthreads();

    const int lane = tid & 63, wave = tid >> 6, quad = lane >> 4, l15 = lane & 15;
    const int j0 = (jb << 6) + (wave << 4);
    const int pboff = (((b << 8) + (j0 + l15)) << 8);
    const float* pbq0 = pbp + pboff;
    const float* pbq1 = pbp + (1 << 18) + pboff;

    f32x4 acc[4][4];   // [ii][eb]
#pragma unroll
    for (int ii = 0; ii < 4; ++ii)
#pragma unroll
        for (int eb = 0; eb < 4; ++eb) acc[ii][eb] = (f32x4){0.f, 0.f, 0.f, 0.f};

    float b2v[4];
#pragma unroll
    for (int eb = 0; eb < 4; ++eb) b2v[eb] = b2[(eb << 4) + l15];

    // software pipeline: raw pb vectors for k0=0
    const int gq = quad << 3;
    f32x4 n00 = *reinterpret_cast<const f32x4*>(pbq0 + gq);
    f32x4 n01 = *reinterpret_cast<const f32x4*>(pbq1 + gq);
    f32x4 n10 = *reinterpret_cast<const f32x4*>(pbq0 + gq + 4);
    f32x4 n11 = *reinterpret_cast<const f32x4*>(pbq1 + gq + 4);

    for (int k0 = 0; k0 < 8; ++k0) {
        const int g = (k0 << 5) + gq;
        const f32x4 p0 = n00 + n01;
        const f32x4 p1 = n10 + n11;
        const int gn = (((k0 + 1) & 7) << 5) + gq;
        n00 = *reinterpret_cast<const f32x4*>(pbq0 + gn);
        n01 = *reinterpret_cast<const f32x4*>(pbq1 + gn);
        n10 = *reinterpret_cast<const f32x4*>(pbq0 + gn + 4);
        n11 = *reinterpret_cast<const f32x4*>(pbq1 + gn + 4);

        s16x8 bfrag[4];
#pragma unroll
        for (int eb = 0; eb < 4; ++eb)
            bfrag[eb] = w2s[((k0 << 2) + eb) * 64 + lane];

#pragma unroll
        for (int ii = 0; ii < 4; ++ii) {
            const f32x4 q0 = *reinterpret_cast<const f32x4*>(&pab1[ii][g]);
            const f32x4 q1 = *reinterpret_cast<const f32x4*>(&pab1[ii][g + 4]);
            float z[8], dd[8];
#pragma unroll
            for (int jj = 0; jj < 4; ++jj) {
                z[jj]     = q0[jj] + p0[jj];
                z[4 + jj] = q1[jj] + p1[jj];
            }
#pragma unroll
            for (int jj = 0; jj < 8; ++jj) {
                const float u = fmaxf(z[jj], -18.0f);
                dd[jj] = 1.0f + __builtin_amdgcn_exp2f(u * -1.44269504f);
            }
            const float p01 = dd[0] * dd[1], p23 = dd[2] * dd[3];
            const float p45 = dd[4] * dd[5], p67 = dd[6] * dd[7];
            const float P4a = p01 * p23, P4b = p45 * p67;
            const float r8 = __builtin_amdgcn_rcpf(P4a * P4b);
            const float ra = r8 * P4b, rb = r8 * P4a;
            const float m0 = ra * p23, m1 = ra * p01;
            const float m2 = rb * p67, m3 = rb * p45;
            float s[8];
            s[0] = z[0] * (m0 * dd[1]); s[1] = z[1] * (m0 * dd[0]);
            s[2] = z[2] * (m1 * dd[3]); s[3] = z[3] * (m1 * dd[2]);
            s[4] = z[4] * (m2 * dd[5]); s[5] = z[5] * (m2 * dd[4]);
            s[6] = z[6] * (m3 * dd[7]); s[7] = z[7] * (m3 * dd[6]);
            u32x4 ap;
            ap[0] = cvtpk(s[0], s[1]); ap[1] = cvtpk(s[2], s[3]);
            ap[2] = cvtpk(s[4], s[5]); ap[3] = cvtpk(s[6], s[7]);
            const s16x8 a = __builtin_bit_cast(s16x8, ap);
#pragma unroll
            for (int eb = 0; eb < 4; ++eb)
                acc[ii][eb] = __builtin_amdgcn_mfma_f32_16x16x32_bf16(a, bfrag[eb], acc[ii][eb], 0, 0, 0);
        }
    }

#pragma unroll
    for (int ii = 0; ii < 4; ++ii) {
        const int obase = (((((b << 8) + i0 + ii) << 8) + j0 + (quad << 2)) << 6) + l15;
#pragma unroll
        for (int eb = 0; eb < 4; ++eb) {
#pragma unroll
            for (int r = 0; r < 4; ++r)
                out[obase + (r << 6) + (eb << 4)] = acc[ii][eb][r] + b2v[eb];
        }
    }
}

extern "C" void kernel_launch(void* const* d_in, const int* in_sizes, int n_in,
                              void* d_out, int out_size, void* d_ws, size_t ws_size,
                              hipStream_t stream) {
    const float* x = 0; const float* Win = 0; const float* bin = 0;
    const float* W1 = 0; const float* b1 = 0; const float* W2 = 0; const float* b2 = 0;
    for (int idx = 0; idx < n_in; ++idx) {
        const int s = in_sizes[idx];
        if (s == 262144) x = (const float*)d_in[idx];
        else if (s == 131072) W1 = (const float*)d_in[idx];
        else if (s == 65536) Win = (const float*)d_in[idx];
        else if (s == 16384) W2 = (const float*)d_in[idx];
        else if (s == 64) b2 = (const float*)d_in[idx];
        else if (s == 256) { if (!bin) bin = (const float*)d_in[idx]; else b1 = (const float*)d_in[idx]; }
    }

    // ws layout (floats): hp 4x(1<<18) | pap 2x(1<<18) | pbp 2x(1<<18) | W2f 8192 (32 KB)
    float* ws  = (float*)d_ws;
    float* hp  = ws;
    float* pap = hp + (4 << 18);
    float* pbp = pap + (2 << 18);
    float* w2f = pbp + (2 << 18);

    hipLaunchKernelGGL(k_xh,  dim3(16, 4, 5), dim3(256), 0, stream, x, Win, hp, W2, (s16x8*)w2f);
    hipLaunchKernelGGL(k_pab, dim3(16, 8, 2), dim3(256), 0, stream, hp, W1, bin, pap, pbp);
    hipLaunchKernelGGL(k_out, dim3(4, 64, 4), dim3(256), 0, stream,
                       pap, pbp, b1, (const s16x8*)w2f, b2, (float*)d_out);
}

// Round 16
// 115.805 us; speedup vs baseline: 1.0570x; 1.0570x over previous
//
#include <hip/hip_runtime.h>

#define DIN 256
#define DHID 256
#define DEDGE 64
#define BS 136      // bf16 LDS tile row stride (shorts), 128-col tiles: 272 B
#define BS2 72      // bf16 LDS tile row stride (shorts), 64-col tiles: 144 B

typedef float f32x4 __attribute__((ext_vector_type(4)));
typedef short s16x8 __attribute__((ext_vector_type(8)));
typedef unsigned int u32x2 __attribute__((ext_vector_type(2)));
typedef unsigned int u32x4 __attribute__((ext_vector_type(4)));

// HW RNE pack: dst = {bf16(lo), bf16(hi)}
__device__ __forceinline__ unsigned int cvtpk(float lo, float hi) {
    unsigned int r;
    asm("v_cvt_pk_bf16_f32 %0, %1, %2" : "=v"(r) : "v"(lo), "v"(hi));
    return r;
}

// split fp32x4 -> hi bf16 pair + lo bf16 pair (bf16x3 decomposition)
__device__ __forceinline__ void split4(const f32x4 v, u32x2& hi, u32x2& lo) {
    const unsigned int h0 = cvtpk(v[0], v[1]), h1 = cvtpk(v[2], v[3]);
    f32x4 hf;
    hf[0] = __builtin_bit_cast(float, h0 << 16);
    hf[1] = __builtin_bit_cast(float, h0 & 0xffff0000u);
    hf[2] = __builtin_bit_cast(float, h1 << 16);
    hf[3] = __builtin_bit_cast(float, h1 & 0xffff0000u);
    const f32x4 l = v - hf;
    hi = (u32x2){h0, h1};
    lo = (u32x2){cvtpk(l[0], l[1]), cvtpk(l[2], l[3])};
}

// -------- Kernel 1 (MFMA bf16x3): hp[kc][m][n] = sum_{k in 64-chunk kc} x[m][k]*Win[n][k]
// EXACT R6 version: grid (16 mt, 4 nt, 5): z<4 = GEMM K-chunks (256 blocks);
// z==4 = W2->fragment-order precompute spread over the 64 (x,y) blocks.
__global__ __launch_bounds__(256) void k_xh(
    const float* __restrict__ x, const float* __restrict__ Win,
    float* __restrict__ hp, const float* __restrict__ W2, s16x8* __restrict__ W2f)
{
    const int tid = threadIdx.x;
    if (blockIdx.z == 4) {
        if (tid < 32) {
            const int f = (((blockIdx.x << 2) + blockIdx.y) << 5) + tid;
            const int l15f = f & 15, qf = (f >> 4) & 3, ebf = (f >> 6) & 3, k0f = f >> 8;
            const int row = (ebf << 4) + l15f;
            const int col = (k0f << 5) + (qf << 3);
            const f32x4 w0 = *reinterpret_cast<const f32x4*>(&W2[row * DHID + col]);
            const f32x4 w1 = *reinterpret_cast<const f32x4*>(&W2[row * DHID + col + 4]);
            u32x4 wp;
            wp[0] = cvtpk(w0[0], w0[1]); wp[1] = cvtpk(w0[2], w0[3]);
            wp[2] = cvtpk(w1[0], w1[1]); wp[3] = cvtpk(w1[2], w1[3]);
            W2f[f] = __builtin_bit_cast(s16x8, wp);
        }
        return;
    }

    __shared__ unsigned short Ahi[64 * BS2], Alo[64 * BS2];
    __shared__ unsigned short Bhi[64 * BS2], Blo[64 * BS2];   // 4 x 9.2 KB = 36.9 KB
    const int m0 = blockIdx.x << 6, n0 = blockIdx.y << 6, k0 = blockIdx.z << 6;

    const int srow = tid >> 2, sc0 = (tid & 3) << 2;
    {
        const float* xA = x + (m0 + srow) * DIN + k0 + sc0;
        const float* wB = Win + (n0 + srow) * DIN + k0 + sc0;
#pragma unroll
        for (int g2 = 0; g2 < 4; ++g2) {
            const int c = g2 << 4;
            const int la = srow * BS2 + sc0 + c;
            u32x2 hi, lo;
            split4(*reinterpret_cast<const f32x4*>(xA + c), hi, lo);
            *reinterpret_cast<u32x2*>(&Ahi[la]) = hi;
            *reinterpret_cast<u32x2*>(&Alo[la]) = lo;
            split4(*reinterpret_cast<const f32x4*>(wB + c), hi, lo);
            *reinterpret_cast<u32x2*>(&Bhi[la]) = hi;
            *reinterpret_cast<u32x2*>(&Blo[la]) = lo;
        }
    }
    __syncthreads();

    const int lane = tid & 63, wave = tid >> 6, quad = lane >> 4, l15 = lane & 15;
    const int arow = (wave << 4) + l15;

    f32x4 acc[4];
#pragma unroll
    for (int nb = 0; nb < 4; ++nb) acc[nb] = (f32x4){0.f, 0.f, 0.f, 0.f};

#pragma unroll
    for (int ks = 0; ks < 2; ++ks) {
        const int kcol = (ks << 5) + (quad << 3);
        const s16x8 ahi = *reinterpret_cast<const s16x8*>(&Ahi[arow * BS2 + kcol]);
        const s16x8 alo = *reinterpret_cast<const s16x8*>(&Alo[arow * BS2 + kcol]);
#pragma unroll
        for (int nb = 0; nb < 4; ++nb) {
            const int brow = (nb << 4) + l15;
            const s16x8 bhi = *reinterpret_cast<const s16x8*>(&Bhi[brow * BS2 + kcol]);
            const s16x8 blo = *reinterpret_cast<const s16x8*>(&Blo[brow * BS2 + kcol]);
            acc[nb] = __builtin_amdgcn_mfma_f32_16x16x32_bf16(ahi, bhi, acc[nb], 0, 0, 0);
            acc[nb] = __builtin_amdgcn_mfma_f32_16x16x32_bf16(ahi, blo, acc[nb], 0, 0, 0);
            acc[nb] = __builtin_amdgcn_mfma_f32_16x16x32_bf16(alo, bhi, acc[nb], 0, 0, 0);
        }
    }

    float* dst = hp + ((size_t)blockIdx.z << 18);
    const int mrow = m0 + (wave << 4) + (quad << 2);
#pragma unroll
    for (int nb = 0; nb < 4; ++nb)
#pragma unroll
        for (int r = 0; r < 4; ++r)
            dst[(mrow + r) * DHID + n0 + (nb << 4) + l15] = acc[nb][r];
}

// -------- Kernel 2 (MFMA bf16x3): pap/pbp[kc][m][g], EXACT R6/R12 version.
__global__ __launch_bounds__(256) void k_pab(
    const float* __restrict__ hp, const float* __restrict__ W1,
    const float* __restrict__ bin, float* __restrict__ pap, float* __restrict__ pbp)
{
    __shared__ unsigned short Ahi[64 * BS], Alo[64 * BS];
    __shared__ unsigned short Bhi[64 * BS], Blo[64 * BS];   // 4 x 17.4 KB = 69.6 KB
    const int m0 = blockIdx.x << 6;
    const int half = blockIdx.y >> 2;
    const int n0 = (blockIdx.y & 3) << 6;
    const int kc = blockIdx.z;
    const int tid = threadIdx.x;
    const int k0 = kc << 7;

    const int srow = tid >> 2, sc0 = (tid & 3) << 2;
    {
        const float* hpA = hp + (m0 + srow) * DHID + k0 + sc0;
        const float* w1B = W1 + (n0 + srow) * 512 + (half << 8) + k0 + sc0;
        const float* binp = bin + k0 + sc0;
#pragma unroll
        for (int g2 = 0; g2 < 8; ++g2) {
            const int c = g2 << 4;
            f32x4 av = *reinterpret_cast<const f32x4*>(hpA + c);
            av += *reinterpret_cast<const f32x4*>(hpA + c + (1 << 18));
            av += *reinterpret_cast<const f32x4*>(hpA + c + (2 << 18));
            av += *reinterpret_cast<const f32x4*>(hpA + c + (3 << 18));
            av += *reinterpret_cast<const f32x4*>(binp + c);
            const int la = srow * BS + sc0 + c;
            u32x2 hi, lo;
            split4(av, hi, lo);
            *reinterpret_cast<u32x2*>(&Ahi[la]) = hi;
            *reinterpret_cast<u32x2*>(&Alo[la]) = lo;
            split4(*reinterpret_cast<const f32x4*>(w1B + c), hi, lo);
            *reinterpret_cast<u32x2*>(&Bhi[la]) = hi;
            *reinterpret_cast<u32x2*>(&Blo[la]) = lo;
        }
    }
    __syncthreads();

    const int lane = tid & 63, wave = tid >> 6, quad = lane >> 4, l15 = lane & 15;
    const int arow = (wave << 4) + l15;

    f32x4 acc[4];
#pragma unroll
    for (int nb = 0; nb < 4; ++nb) acc[nb] = (f32x4){0.f, 0.f, 0.f, 0.f};

#pragma unroll
    for (int ks = 0; ks < 4; ++ks) {
        const int kcol = (ks << 5) + (quad << 3);
        const s16x8 ahi = *reinterpret_cast<const s16x8*>(&Ahi[arow * BS + kcol]);
        const s16x8 alo = *reinterpret_cast<const s16x8*>(&Alo[arow * BS + kcol]);
#pragma unroll
        for (int nb = 0; nb < 4; ++nb) {
            const int brow = (nb << 4) + l15;
            const s16x8 bhi = *reinterpret_cast<const s16x8*>(&Bhi[brow * BS + kcol]);
            const s16x8 blo = *reinterpret_cast<const s16x8*>(&Blo[brow * BS + kcol]);
            acc[nb] = __builtin_amdgcn_mfma_f32_16x16x32_bf16(ahi, bhi, acc[nb], 0, 0, 0);
            acc[nb] = __builtin_amdgcn_mfma_f32_16x16x32_bf16(ahi, blo, acc[nb], 0, 0, 0);
            acc[nb] = __builtin_amdgcn_mfma_f32_16x16x32_bf16(alo, bhi, acc[nb], 0, 0, 0);
        }
    }

    float* dst = (half ? pbp : pap) + ((size_t)kc << 18);
    const int mrow = m0 + (wave << 4) + (quad << 2);
#pragma unroll
    for (int nb = 0; nb < 4; ++nb)
#pragma unroll
        for (int r = 0; r < 4; ++r)
            dst[(mrow + r) * DHID + n0 + (nb << 4) + l15] = acc[nb][r];
}

// -------- Kernel 3: fused z=silu(pa_i+pb_j+b1); out = z@W2^T + b2 (MFMA) ----
// EXACT R12 structure (runtime k0 loop, 1-deep pb pipeline, grid (4,64,4),
// plain stores, epilogue b2). ONLY change: silu adds/muls expressed as f32x4
// vector ops with in-place temps -> v_pk_add_f32/v_pk_mul_f32 (2 elem/inst),
// cutting ~16 of ~52 arithmetic insts per 8-elem group. Same op pairing and
// order as R12 -> bit-identical results. trans count unchanged (R15 showed
// trans is cheap; VALU issue count is the binding resource).
__global__ __launch_bounds__(256) void k_out(
    const float* __restrict__ pap, const float* __restrict__ pbp,
    const float* __restrict__ b1, const s16x8* __restrict__ W2f,
    const float* __restrict__ b2, float* __restrict__ out)
{
    __shared__ s16x8 w2s[2048];      // 32 KB, fragment layout
    __shared__ float pab1[4][DHID];  // 4 KB

    const int jb = blockIdx.x, i0 = blockIdx.y << 2, b = blockIdx.z;
    const int tid = threadIdx.x;

    {
        const float b1v = b1[tid];
#pragma unroll
        for (int ii = 0; ii < 4; ++ii) {
            const int off = (((b << 8) + i0 + ii) << 8) + tid;
            pab1[ii][tid] = pap[off] + pap[off + (1 << 18)] + b1v;
        }
    }
#pragma unroll
    for (int it = 0; it < 8; ++it)
        w2s[tid + (it << 8)] = W2f[tid + (it << 8)];
    __syncthreads();

    const int lane = tid & 63, wave = tid >> 6, quad = lane >> 4, l15 = lane & 15;
    const int j0 = (jb << 6) + (wave << 4);
    const int pboff = (((b << 8) + (j0 + l15)) << 8);
    const float* pbq0 = pbp + pboff;
    const float* pbq1 = pbp + (1 << 18) + pboff;

    f32x4 acc[4][4];   // [ii][eb]
#pragma unroll
    for (int ii = 0; ii < 4; ++ii)
#pragma unroll
        for (int eb = 0; eb < 4; ++eb) acc[ii][eb] = (f32x4){0.f, 0.f, 0.f, 0.f};

    float b2v[4];
#pragma unroll
    for (int eb = 0; eb < 4; ++eb) b2v[eb] = b2[(eb << 4) + l15];

    const f32x4 nl2  = {-1.44269504f, -1.44269504f, -1.44269504f, -1.44269504f};
    const f32x4 one4 = {1.f, 1.f, 1.f, 1.f};

    // software pipeline: raw pb vectors for k0=0
    const int gq = quad << 3;
    f32x4 n00 = *reinterpret_cast<const f32x4*>(pbq0 + gq);
    f32x4 n01 = *reinterpret_cast<const f32x4*>(pbq1 + gq);
    f32x4 n10 = *reinterpret_cast<const f32x4*>(pbq0 + gq + 4);
    f32x4 n11 = *reinterpret_cast<const f32x4*>(pbq1 + gq + 4);

    for (int k0 = 0; k0 < 8; ++k0) {
        const int g = (k0 << 5) + gq;
        const f32x4 p0 = n00 + n01;
        const f32x4 p1 = n10 + n11;
        const int gn = (((k0 + 1) & 7) << 5) + gq;
        n00 = *reinterpret_cast<const f32x4*>(pbq0 + gn);
        n01 = *reinterpret_cast<const f32x4*>(pbq1 + gn);
        n10 = *reinterpret_cast<const f32x4*>(pbq0 + gn + 4);
        n11 = *reinterpret_cast<const f32x4*>(pbq1 + gn + 4);

        s16x8 bfrag[4];
#pragma unroll
        for (int eb = 0; eb < 4; ++eb)
            bfrag[eb] = w2s[((k0 << 2) + eb) * 64 + lane];

#pragma unroll
        for (int ii = 0; ii < 4; ++ii) {
            const f32x4 q0 = *reinterpret_cast<const f32x4*>(&pab1[ii][g]);
            const f32x4 q1 = *reinterpret_cast<const f32x4*>(&pab1[ii][g + 4]);
            const f32x4 z0 = q0 + p0;            // pk_add x2
            const f32x4 z1 = q1 + p1;
            f32x4 t0 = z0 * nl2;                 // pk_mul x2 (exp arg)
            f32x4 t1 = z1 * nl2;
#pragma unroll
            for (int jj = 0; jj < 4; ++jj) {     // trans (unchanged count)
                t0[jj] = __builtin_amdgcn_exp2f(t0[jj]);
                t1[jj] = __builtin_amdgcn_exp2f(t1[jj]);
            }
            t0 += one4;                          // pk_add x2
            t1 += one4;
#pragma unroll
            for (int jj = 0; jj < 4; ++jj) {     // trans (unchanged count)
                t0[jj] = __builtin_amdgcn_rcpf(t0[jj]);
                t1[jj] = __builtin_amdgcn_rcpf(t1[jj]);
            }
            const f32x4 s0 = z0 * t0;            // pk_mul x2
            const f32x4 s1 = z1 * t1;
            u32x4 ap;
            ap[0] = cvtpk(s0[0], s0[1]); ap[1] = cvtpk(s0[2], s0[3]);
            ap[2] = cvtpk(s1[0], s1[1]); ap[3] = cvtpk(s1[2], s1[3]);
            const s16x8 a = __builtin_bit_cast(s16x8, ap);
#pragma unroll
            for (int eb = 0; eb < 4; ++eb)
                acc[ii][eb] = __builtin_amdgcn_mfma_f32_16x16x32_bf16(a, bfrag[eb], acc[ii][eb], 0, 0, 0);
        }
    }

#pragma unroll
    for (int ii = 0; ii < 4; ++ii) {
        const int obase = (((((b << 8) + i0 + ii) << 8) + j0 + (quad << 2)) << 6) + l15;
#pragma unroll
        for (int eb = 0; eb < 4; ++eb) {
#pragma unroll
            for (int r = 0; r < 4; ++r)
                out[obase + (r << 6) + (eb << 4)] = acc[ii][eb][r] + b2v[eb];
        }
    }
}

extern "C" void kernel_launch(void* const* d_in, const int* in_sizes, int n_in,
                              void* d_out, int out_size, void* d_ws, size_t ws_size,
                              hipStream_t stream) {
    const float* x = 0; const float* Win = 0; const float* bin = 0;
    const float* W1 = 0; const float* b1 = 0; const float* W2 = 0; const float* b2 = 0;
    for (int idx = 0; idx < n_in; ++idx) {
        const int s = in_sizes[idx];
        if (s == 262144) x = (const float*)d_in[idx];
        else if (s == 131072) W1 = (const float*)d_in[idx];
        else if (s == 65536) Win = (const float*)d_in[idx];
        else if (s == 16384) W2 = (const float*)d_in[idx];
        else if (s == 64) b2 = (const float*)d_in[idx];
        else if (s == 256) { if (!bin) bin = (const float*)d_in[idx]; else b1 = (const float*)d_in[idx]; }
    }

    // ws layout (floats): hp 4x(1<<18) | pap 2x(1<<18) | pbp 2x(1<<18) | W2f 8192 (32 KB)
    float* ws  = (float*)d_ws;
    float* hp  = ws;
    float* pap = hp + (4 << 18);
    float* pbp = pap + (2 << 18);
    float* w2f = pbp + (2 << 18);

    hipLaunchKernelGGL(k_xh,  dim3(16, 4, 5), dim3(256), 0, stream, x, Win, hp, W2, (s16x8*)w2f);
    hipLaunchKernelGGL(k_pab, dim3(16, 8, 2), dim3(256), 0, stream, hp, W1, bin, pap, pbp);
    hipLaunchKernelGGL(k_out, dim3(4, 64, 4), dim3(256), 0, stream,
                       pap, pbp, b1, (const s16x8*)w2f, b2, (float*)d_out);
}

// Round 17
// 114.997 us; speedup vs baseline: 1.0644x; 1.0070x over previous
//
#include <hip/hip_runtime.h>

#define DIN 256
#define DHID 256
#define DEDGE 64
#define BS 136      // bf16 LDS tile row stride (shorts), 128-col tiles: 272 B
#define BS2 72      // bf16 LDS tile row stride (shorts), 64-col tiles: 144 B

typedef float f32x4 __attribute__((ext_vector_type(4)));
typedef float f32x2 __attribute__((ext_vector_type(2)));
typedef short s16x8 __attribute__((ext_vector_type(8)));
typedef unsigned int u32x2 __attribute__((ext_vector_type(2)));
typedef unsigned int u32x4 __attribute__((ext_vector_type(4)));

// HW RNE pack: dst = {bf16(lo), bf16(hi)}
__device__ __forceinline__ unsigned int cvtpk(float lo, float hi) {
    unsigned int r;
    asm("v_cvt_pk_bf16_f32 %0, %1, %2" : "=v"(r) : "v"(lo), "v"(hi));
    return r;
}

// forced packed fp32 math (VOP3P) — compiler cannot scalarize asm
__device__ __forceinline__ f32x2 pkadd(f32x2 a, f32x2 b) {
    f32x2 r;
    asm("v_pk_add_f32 %0, %1, %2" : "=v"(r) : "v"(a), "v"(b));
    return r;
}
__device__ __forceinline__ f32x2 pkmul(f32x2 a, f32x2 b) {
    f32x2 r;
    asm("v_pk_mul_f32 %0, %1, %2" : "=v"(r) : "v"(a), "v"(b));
    return r;
}
__device__ __forceinline__ f32x2 vlo(f32x4 v) { f32x2 r; r[0] = v[0]; r[1] = v[1]; return r; }
__device__ __forceinline__ f32x2 vhi(f32x4 v) { f32x2 r; r[0] = v[2]; r[1] = v[3]; return r; }

// split fp32x4 -> hi bf16 pair + lo bf16 pair (bf16x3 decomposition)
__device__ __forceinline__ void split4(const f32x4 v, u32x2& hi, u32x2& lo) {
    const unsigned int h0 = cvtpk(v[0], v[1]), h1 = cvtpk(v[2], v[3]);
    f32x4 hf;
    hf[0] = __builtin_bit_cast(float, h0 << 16);
    hf[1] = __builtin_bit_cast(float, h0 & 0xffff0000u);
    hf[2] = __builtin_bit_cast(float, h1 << 16);
    hf[3] = __builtin_bit_cast(float, h1 & 0xffff0000u);
    const f32x4 l = v - hf;
    hi = (u32x2){h0, h1};
    lo = (u32x2){cvtpk(l[0], l[1]), cvtpk(l[2], l[3])};
}

// -------- Kernel 1 (MFMA bf16x3): hp[kc][m][n] = sum_{k in 64-chunk kc} x[m][k]*Win[n][k]
// EXACT R6 version: grid (16 mt, 4 nt, 5): z<4 = GEMM K-chunks (256 blocks);
// z==4 = W2->fragment-order precompute spread over the 64 (x,y) blocks.
__global__ __launch_bounds__(256) void k_xh(
    const float* __restrict__ x, const float* __restrict__ Win,
    float* __restrict__ hp, const float* __restrict__ W2, s16x8* __restrict__ W2f)
{
    const int tid = threadIdx.x;
    if (blockIdx.z == 4) {
        if (tid < 32) {
            const int f = (((blockIdx.x << 2) + blockIdx.y) << 5) + tid;
            const int l15f = f & 15, qf = (f >> 4) & 3, ebf = (f >> 6) & 3, k0f = f >> 8;
            const int row = (ebf << 4) + l15f;
            const int col = (k0f << 5) + (qf << 3);
            const f32x4 w0 = *reinterpret_cast<const f32x4*>(&W2[row * DHID + col]);
            const f32x4 w1 = *reinterpret_cast<const f32x4*>(&W2[row * DHID + col + 4]);
            u32x4 wp;
            wp[0] = cvtpk(w0[0], w0[1]); wp[1] = cvtpk(w0[2], w0[3]);
            wp[2] = cvtpk(w1[0], w1[1]); wp[3] = cvtpk(w1[2], w1[3]);
            W2f[f] = __builtin_bit_cast(s16x8, wp);
        }
        return;
    }

    __shared__ unsigned short Ahi[64 * BS2], Alo[64 * BS2];
    __shared__ unsigned short Bhi[64 * BS2], Blo[64 * BS2];   // 4 x 9.2 KB = 36.9 KB
    const int m0 = blockIdx.x << 6, n0 = blockIdx.y << 6, k0 = blockIdx.z << 6;

    const int srow = tid >> 2, sc0 = (tid & 3) << 2;
    {
        const float* xA = x + (m0 + srow) * DIN + k0 + sc0;
        const float* wB = Win + (n0 + srow) * DIN + k0 + sc0;
#pragma unroll
        for (int g2 = 0; g2 < 4; ++g2) {
            const int c = g2 << 4;
            const int la = srow * BS2 + sc0 + c;
            u32x2 hi, lo;
            split4(*reinterpret_cast<const f32x4*>(xA + c), hi, lo);
            *reinterpret_cast<u32x2*>(&Ahi[la]) = hi;
            *reinterpret_cast<u32x2*>(&Alo[la]) = lo;
            split4(*reinterpret_cast<const f32x4*>(wB + c), hi, lo);
            *reinterpret_cast<u32x2*>(&Bhi[la]) = hi;
            *reinterpret_cast<u32x2*>(&Blo[la]) = lo;
        }
    }
    __syncthreads();

    const int lane = tid & 63, wave = tid >> 6, quad = lane >> 4, l15 = lane & 15;
    const int arow = (wave << 4) + l15;

    f32x4 acc[4];
#pragma unroll
    for (int nb = 0; nb < 4; ++nb) acc[nb] = (f32x4){0.f, 0.f, 0.f, 0.f};

#pragma unroll
    for (int ks = 0; ks < 2; ++ks) {
        const int kcol = (ks << 5) + (quad << 3);
        const s16x8 ahi = *reinterpret_cast<const s16x8*>(&Ahi[arow * BS2 + kcol]);
        const s16x8 alo = *reinterpret_cast<const s16x8*>(&Alo[arow * BS2 + kcol]);
#pragma unroll
        for (int nb = 0; nb < 4; ++nb) {
            const int brow = (nb << 4) + l15;
            const s16x8 bhi = *reinterpret_cast<const s16x8*>(&Bhi[brow * BS2 + kcol]);
            const s16x8 blo = *reinterpret_cast<const s16x8*>(&Blo[brow * BS2 + kcol]);
            acc[nb] = __builtin_amdgcn_mfma_f32_16x16x32_bf16(ahi, bhi, acc[nb], 0, 0, 0);
            acc[nb] = __builtin_amdgcn_mfma_f32_16x16x32_bf16(ahi, blo, acc[nb], 0, 0, 0);
            acc[nb] = __builtin_amdgcn_mfma_f32_16x16x32_bf16(alo, bhi, acc[nb], 0, 0, 0);
        }
    }

    float* dst = hp + ((size_t)blockIdx.z << 18);
    const int mrow = m0 + (wave << 4) + (quad << 2);
#pragma unroll
    for (int nb = 0; nb < 4; ++nb)
#pragma unroll
        for (int r = 0; r < 4; ++r)
            dst[(mrow + r) * DHID + n0 + (nb << 4) + l15] = acc[nb][r];
}

// -------- Kernel 2 (MFMA bf16x3): pap/pbp[kc][m][g], EXACT R6/R12 version.
__global__ __launch_bounds__(256) void k_pab(
    const float* __restrict__ hp, const float* __restrict__ W1,
    const float* __restrict__ bin, float* __restrict__ pap, float* __restrict__ pbp)
{
    __shared__ unsigned short Ahi[64 * BS], Alo[64 * BS];
    __shared__ unsigned short Bhi[64 * BS], Blo[64 * BS];   // 4 x 17.4 KB = 69.6 KB
    const int m0 = blockIdx.x << 6;
    const int half = blockIdx.y >> 2;
    const int n0 = (blockIdx.y & 3) << 6;
    const int kc = blockIdx.z;
    const int tid = threadIdx.x;
    const int k0 = kc << 7;

    const int srow = tid >> 2, sc0 = (tid & 3) << 2;
    {
        const float* hpA = hp + (m0 + srow) * DHID + k0 + sc0;
        const float* w1B = W1 + (n0 + srow) * 512 + (half << 8) + k0 + sc0;
        const float* binp = bin + k0 + sc0;
#pragma unroll
        for (int g2 = 0; g2 < 8; ++g2) {
            const int c = g2 << 4;
            f32x4 av = *reinterpret_cast<const f32x4*>(hpA + c);
            av += *reinterpret_cast<const f32x4*>(hpA + c + (1 << 18));
            av += *reinterpret_cast<const f32x4*>(hpA + c + (2 << 18));
            av += *reinterpret_cast<const f32x4*>(hpA + c + (3 << 18));
            av += *reinterpret_cast<const f32x4*>(binp + c);
            const int la = srow * BS + sc0 + c;
            u32x2 hi, lo;
            split4(av, hi, lo);
            *reinterpret_cast<u32x2*>(&Ahi[la]) = hi;
            *reinterpret_cast<u32x2*>(&Alo[la]) = lo;
            split4(*reinterpret_cast<const f32x4*>(w1B + c), hi, lo);
            *reinterpret_cast<u32x2*>(&Bhi[la]) = hi;
            *reinterpret_cast<u32x2*>(&Blo[la]) = lo;
        }
    }
    __syncthreads();

    const int lane = tid & 63, wave = tid >> 6, quad = lane >> 4, l15 = lane & 15;
    const int arow = (wave << 4) + l15;

    f32x4 acc[4];
#pragma unroll
    for (int nb = 0; nb < 4; ++nb) acc[nb] = (f32x4){0.f, 0.f, 0.f, 0.f};

#pragma unroll
    for (int ks = 0; ks < 4; ++ks) {
        const int kcol = (ks << 5) + (quad << 3);
        const s16x8 ahi = *reinterpret_cast<const s16x8*>(&Ahi[arow * BS + kcol]);
        const s16x8 alo = *reinterpret_cast<const s16x8*>(&Alo[arow * BS + kcol]);
#pragma unroll
        for (int nb = 0; nb < 4; ++nb) {
            const int brow = (nb << 4) + l15;
            const s16x8 bhi = *reinterpret_cast<const s16x8*>(&Bhi[brow * BS + kcol]);
            const s16x8 blo = *reinterpret_cast<const s16x8*>(&Blo[brow * BS + kcol]);
            acc[nb] = __builtin_amdgcn_mfma_f32_16x16x32_bf16(ahi, bhi, acc[nb], 0, 0, 0);
            acc[nb] = __builtin_amdgcn_mfma_f32_16x16x32_bf16(ahi, blo, acc[nb], 0, 0, 0);
            acc[nb] = __builtin_amdgcn_mfma_f32_16x16x32_bf16(alo, bhi, acc[nb], 0, 0, 0);
        }
    }

    float* dst = (half ? pbp : pap) + ((size_t)kc << 18);
    const int mrow = m0 + (wave << 4) + (quad << 2);
#pragma unroll
    for (int nb = 0; nb < 4; ++nb)
#pragma unroll
        for (int r = 0; r < 4; ++r)
            dst[(mrow + r) * DHID + n0 + (nb << 4) + l15] = acc[nb][r];
}

// -------- Kernel 3: fused z=silu(pa_i+pb_j+b1); out = z@W2^T + b2 (MFMA) ----
// EXACT R12 structure (runtime k0 loop, 1-deep pb pipeline, grid (4,64,4),
// plain stores, epilogue b2). ONLY change vs R12: silu adds/muls forced to
// v_pk_add_f32/v_pk_mul_f32 via inline asm on f32x2 pairs (2 elem/inst,
// cannot be scalarized). Same element pairing and op order as R12 ->
// bit-identical results. trans count unchanged.
__global__ __launch_bounds__(256) void k_out(
    const float* __restrict__ pap, const float* __restrict__ pbp,
    const float* __restrict__ b1, const s16x8* __restrict__ W2f,
    const float* __restrict__ b2, float* __restrict__ out)
{
    __shared__ s16x8 w2s[2048];      // 32 KB, fragment layout
    __shared__ float pab1[4][DHID];  // 4 KB

    const int jb = blockIdx.x, i0 = blockIdx.y << 2, b = blockIdx.z;
    const int tid = threadIdx.x;

    {
        const float b1v = b1[tid];
#pragma unroll
        for (int ii = 0; ii < 4; ++ii) {
            const int off = (((b << 8) + i0 + ii) << 8) + tid;
            pab1[ii][tid] = pap[off] + pap[off + (1 << 18)] + b1v;
        }
    }
#pragma unroll
    for (int it = 0; it < 8; ++it)
        w2s[tid + (it << 8)] = W2f[tid + (it << 8)];
    __syncthreads();

    const int lane = tid & 63, wave = tid >> 6, quad = lane >> 4, l15 = lane & 15;
    const int j0 = (jb << 6) + (wave << 4);
    const int pboff = (((b << 8) + (j0 + l15)) << 8);
    const float* pbq0 = pbp + pboff;
    const float* pbq1 = pbp + (1 << 18) + pboff;

    f32x4 acc[4][4];   // [ii][eb]
#pragma unroll
    for (int ii = 0; ii < 4; ++ii)
#pragma unroll
        for (int eb = 0; eb < 4; ++eb) acc[ii][eb] = (f32x4){0.f, 0.f, 0.f, 0.f};

    float b2v[4];
#pragma unroll
    for (int eb = 0; eb < 4; ++eb) b2v[eb] = b2[(eb << 4) + l15];

    const f32x2 nl2 = {-1.44269504f, -1.44269504f};
    const f32x2 one2 = {1.f, 1.f};

    // software pipeline: raw pb vectors for k0=0
    const int gq = quad << 3;
    f32x4 n00 = *reinterpret_cast<const f32x4*>(pbq0 + gq);
    f32x4 n01 = *reinterpret_cast<const f32x4*>(pbq1 + gq);
    f32x4 n10 = *reinterpret_cast<const f32x4*>(pbq0 + gq + 4);
    f32x4 n11 = *reinterpret_cast<const f32x4*>(pbq1 + gq + 4);

    for (int k0 = 0; k0 < 8; ++k0) {
        const int g = (k0 << 5) + gq;
        // consume previous prefetch (packed adds)
        const f32x2 p0a = pkadd(vlo(n00), vlo(n01));
        const f32x2 p0b = pkadd(vhi(n00), vhi(n01));
        const f32x2 p1a = pkadd(vlo(n10), vlo(n11));
        const f32x2 p1b = pkadd(vhi(n10), vhi(n11));
        // issue next prefetch immediately (wraps harmlessly at k0=7)
        const int gn = (((k0 + 1) & 7) << 5) + gq;
        n00 = *reinterpret_cast<const f32x4*>(pbq0 + gn);
        n01 = *reinterpret_cast<const f32x4*>(pbq1 + gn);
        n10 = *reinterpret_cast<const f32x4*>(pbq0 + gn + 4);
        n11 = *reinterpret_cast<const f32x4*>(pbq1 + gn + 4);

        s16x8 bfrag[4];
#pragma unroll
        for (int eb = 0; eb < 4; ++eb)
            bfrag[eb] = w2s[((k0 << 2) + eb) * 64 + lane];

#pragma unroll
        for (int ii = 0; ii < 4; ++ii) {
            const f32x4 q0 = *reinterpret_cast<const f32x4*>(&pab1[ii][g]);
            const f32x4 q1 = *reinterpret_cast<const f32x4*>(&pab1[ii][g + 4]);
            // z = q + p (packed)
            const f32x2 z0a = pkadd(vlo(q0), p0a);
            const f32x2 z0b = pkadd(vhi(q0), p0b);
            const f32x2 z1a = pkadd(vlo(q1), p1a);
            const f32x2 z1b = pkadd(vhi(q1), p1b);
            // t = z * -log2(e) (packed)
            f32x2 t0a = pkmul(z0a, nl2), t0b = pkmul(z0b, nl2);
            f32x2 t1a = pkmul(z1a, nl2), t1b = pkmul(z1b, nl2);
            // e = 2^t (trans, unchanged count)
            t0a[0] = __builtin_amdgcn_exp2f(t0a[0]); t0a[1] = __builtin_amdgcn_exp2f(t0a[1]);
            t0b[0] = __builtin_amdgcn_exp2f(t0b[0]); t0b[1] = __builtin_amdgcn_exp2f(t0b[1]);
            t1a[0] = __builtin_amdgcn_exp2f(t1a[0]); t1a[1] = __builtin_amdgcn_exp2f(t1a[1]);
            t1b[0] = __builtin_amdgcn_exp2f(t1b[0]); t1b[1] = __builtin_amdgcn_exp2f(t1b[1]);
            // d = 1 + e (packed)
            t0a = pkadd(t0a, one2); t0b = pkadd(t0b, one2);
            t1a = pkadd(t1a, one2); t1b = pkadd(t1b, one2);
            // r = 1/d (trans, unchanged count)
            t0a[0] = __builtin_amdgcn_rcpf(t0a[0]); t0a[1] = __builtin_amdgcn_rcpf(t0a[1]);
            t0b[0] = __builtin_amdgcn_rcpf(t0b[0]); t0b[1] = __builtin_amdgcn_rcpf(t0b[1]);
            t1a[0] = __builtin_amdgcn_rcpf(t1a[0]); t1a[1] = __builtin_amdgcn_rcpf(t1a[1]);
            t1b[0] = __builtin_amdgcn_rcpf(t1b[0]); t1b[1] = __builtin_amdgcn_rcpf(t1b[1]);
            // s = z * r (packed)
            const f32x2 s0a = pkmul(z0a, t0a), s0b = pkmul(z0b, t0b);
            const f32x2 s1a = pkmul(z1a, t1a), s1b = pkmul(z1b, t1b);
            u32x4 ap;
            ap[0] = cvtpk(s0a[0], s0a[1]); ap[1] = cvtpk(s0b[0], s0b[1]);
            ap[2] = cvtpk(s1a[0], s1a[1]); ap[3] = cvtpk(s1b[0], s1b[1]);
            const s16x8 a = __builtin_bit_cast(s16x8, ap);
#pragma unroll
            for (int eb = 0; eb < 4; ++eb)
                acc[ii][eb] = __builtin_amdgcn_mfma_f32_16x16x32_bf16(a, bfrag[eb], acc[ii][eb], 0, 0, 0);
        }
    }

#pragma unroll
    for (int ii = 0; ii < 4; ++ii) {
        const int obase = (((((b << 8) + i0 + ii) << 8) + j0 + (quad << 2)) << 6) + l15;
#pragma unroll
        for (int eb = 0; eb < 4; ++eb) {
#pragma unroll
            for (int r = 0; r < 4; ++r)
                out[obase + (r << 6) + (eb << 4)] = acc[ii][eb][r] + b2v[eb];
        }
    }
}

extern "C" void kernel_launch(void* const* d_in, const int* in_sizes, int n_in,
                              void* d_out, int out_size, void* d_ws, size_t ws_size,
                              hipStream_t stream) {
    const float* x = 0; const float* Win = 0; const float* bin = 0;
    const float* W1 = 0; const float* b1 = 0; const float* W2 = 0; const float* b2 = 0;
    for (int idx = 0; idx < n_in; ++idx) {
        const int s = in_sizes[idx];
        if (s == 262144) x = (const float*)d_in[idx];
        else if (s == 131072) W1 = (const float*)d_in[idx];
        else if (s == 65536) Win = (const float*)d_in[idx];
        else if (s == 16384) W2 = (const float*)d_in[idx];
        else if (s == 64) b2 = (const float*)d_in[idx];
        else if (s == 256) { if (!bin) bin = (const float*)d_in[idx]; else b1 = (const float*)d_in[idx]; }
    }

    // ws layout (floats): hp 4x(1<<18) | pap 2x(1<<18) | pbp 2x(1<<18) | W2f 8192 (32 KB)
    float* ws  = (float*)d_ws;
    float* hp  = ws;
    float* pap = hp + (4 << 18);
    float* pbp = pap + (2 << 18);
    float* w2f = pbp + (2 << 18);

    hipLaunchKernelGGL(k_xh,  dim3(16, 4, 5), dim3(256), 0, stream, x, Win, hp, W2, (s16x8*)w2f);
    hipLaunchKernelGGL(k_pab, dim3(16, 8, 2), dim3(256), 0, stream, hp, W1, bin, pap, pbp);
    hipLaunchKernelGGL(k_out, dim3(4, 64, 4), dim3(256), 0, stream,
                       pap, pbp, b1, (const s16x8*)w2f, b2, (float*)d_out);
}